// Round 1
// baseline (2484.781 us; speedup 1.0000x reference)
//
#include <hip/hip_runtime.h>
#include <hip/hip_bf16.h>

// Problem: B=16, LQ=1, LK=8192, D=1024, H=1024
// scores[b,k] = sum_h tanh( (q_b @ W_q)[h] + (keys[b,k] @ W_k)[:,h] ) * w_v[h]
#define BB 16
#define LK 8192
#define DD 1024
#define HH 1024

typedef __attribute__((ext_vector_type(8))) short short8;
typedef __attribute__((ext_vector_type(4))) float f32x4;

__device__ __forceinline__ unsigned short f2bf(float x) {
  unsigned u = __float_as_uint(x);
  u += 0x7fffu + ((u >> 16) & 1u);      // RNE
  return (unsigned short)(u >> 16);
}

__device__ __forceinline__ float fast_tanh(float x) {
  float cx = fminf(fmaxf(x, -15.f), 15.f);
  float e  = __expf(2.f * cx);
  return (e - 1.f) * __builtin_amdgcn_rcpf(e + 1.f);
}

// P1: qh[b][h] = sum_d queries[b][d] * W_q[d][h]   (fp32, tiny)
__global__ __launch_bounds__(256) void qh_kernel(
    const float* __restrict__ q, const float* __restrict__ Wq,
    float* __restrict__ qh) {
  const int b = blockIdx.x;
  const int h = blockIdx.y * 256 + threadIdx.x;
  const float* qb = q + (size_t)b * DD;
  float acc = 0.f;
#pragma unroll 8
  for (int d = 0; d < DD; ++d) acc += qb[d] * Wq[(size_t)d * HH + h];
  qh[b * HH + h] = acc;
}

// P2: WkT[h][d] = bf16(W_k[d][h])  (transpose + convert, 2MB out)
__global__ __launch_bounds__(256) void wkt_kernel(
    const float* __restrict__ Wk, unsigned short* __restrict__ WkT) {
  __shared__ float tile[32][33];
  const int h0 = (blockIdx.x % (HH / 32)) * 32;
  const int d0 = (blockIdx.x / (HH / 32)) * 32;
  const int c  = threadIdx.x & 31;
  const int r0 = threadIdx.x >> 5;   // 0..7
#pragma unroll
  for (int i = 0; i < 4; ++i) {
    int r = r0 + i * 8;
    tile[r][c] = Wk[(size_t)(d0 + r) * HH + h0 + c];
  }
  __syncthreads();
#pragma unroll
  for (int i = 0; i < 4; ++i) {
    int r = r0 + i * 8;
    WkT[(size_t)(h0 + r) * DD + d0 + c] = f2bf(tile[c][r]);
  }
}

// Main fused kernel: block = 32 key-rows (one batch), full K=1024 in LDS (bf16),
// 4 waves as 2(M)x2(N) 16x16 MFMA tiles, loop n over H in steps of 32.
// Epilogue per n-chunk: tanh(acc + qh)*wv, 16-lane butterfly reduce -> row acc.
__global__ __launch_bounds__(256, 2) void fused_kernel(
    const float* __restrict__ keys, const unsigned short* __restrict__ WkT,
    const float* __restrict__ qh, const float* __restrict__ wv,
    float* __restrict__ out) {
  // row stride 2064 B (1024 bf16 + 8 pad) -> banks shift by 4 per row: 2-way max
  __shared__ __align__(16) unsigned char Abuf[32 * 2064];
  __shared__ float qh_s[HH];
  __shared__ float wv_s[HH];
  __shared__ float ssum[2][32];

  const int tid   = threadIdx.x;
  const int mbase = blockIdx.x * 32;
  const int b     = mbase >> 13;   // /8192, blocks never straddle batches

  for (int i = tid; i < HH; i += 256) {
    qh_s[i] = qh[b * HH + i];
    wv_s[i] = wv[i];
  }

  {  // stage keys tile: 32 rows x 1024 fp32 -> bf16 LDS, coalesced 1KB/wave reads
    const float4* src = (const float4*)(keys + (size_t)mbase * DD);
#pragma unroll 4
    for (int i = 0; i < 32; ++i) {
      float4 v = src[i * (DD / 4) + tid];
      ushort4 p;
      p.x = f2bf(v.x); p.y = f2bf(v.y); p.z = f2bf(v.z); p.w = f2bf(v.w);
      *(ushort4*)(Abuf + i * 2064 + tid * 8) = p;
    }
  }
  __syncthreads();

  const int lane = tid & 63;
  const int wid  = tid >> 6;
  const int wm   = wid & 1;    // M-tile within block
  const int wn   = wid >> 1;   // N-phase
  const int l15  = lane & 15;
  const int lg   = lane >> 4;

  const int arow = wm * 16 + l15;                       // A row = lane&15
  const unsigned abase = (unsigned)(arow * 2064 + lg * 16);

  float racc0 = 0.f, racc1 = 0.f, racc2 = 0.f, racc3 = 0.f;

  for (int n0 = wn * 16; n0 < HH; n0 += 32) {
    f32x4 acc = {0.f, 0.f, 0.f, 0.f};
    const unsigned short* bptr = WkT + (size_t)(n0 + l15) * DD + lg * 8;
#pragma unroll 4
    for (int k0 = 0; k0 < DD; k0 += 32) {
      short8 a  = *(const short8*)(Abuf + abase + k0 * 2);  // ds_read_b128
      short8 bv = *(const short8*)(bptr + k0);              // L2-resident W_kT
      acc = __builtin_amdgcn_mfma_f32_16x16x32_bf16(a, bv, acc, 0, 0, 0);
    }
    // C/D layout (m89): col = lane&15 (= h), row = (lane>>4)*4 + r (= key row)
    const float qv  = qh_s[n0 + l15];
    const float wvv = wv_s[n0 + l15];
    float t0 = fast_tanh(acc[0] + qv) * wvv;
    float t1 = fast_tanh(acc[1] + qv) * wvv;
    float t2 = fast_tanh(acc[2] + qv) * wvv;
    float t3 = fast_tanh(acc[3] + qv) * wvv;
#pragma unroll
    for (int off = 1; off < 16; off <<= 1) {
      t0 += __shfl_xor(t0, off);
      t1 += __shfl_xor(t1, off);
      t2 += __shfl_xor(t2, off);
      t3 += __shfl_xor(t3, off);
    }
    racc0 += t0; racc1 += t1; racc2 += t2; racc3 += t3;
  }

  if (l15 == 0) {
    const int r = wm * 16 + lg * 4;
    ssum[wn][r + 0] = racc0;
    ssum[wn][r + 1] = racc1;
    ssum[wn][r + 2] = racc2;
    ssum[wn][r + 3] = racc3;
  }
  __syncthreads();
  if (tid < 32) out[mbase + tid] = ssum[0][tid] + ssum[1][tid];
}

extern "C" void kernel_launch(void* const* d_in, const int* in_sizes, int n_in,
                              void* d_out, int out_size, void* d_ws, size_t ws_size,
                              hipStream_t stream) {
  const float* queries = (const float*)d_in[0];  // [16,1,1024]
  const float* keys    = (const float*)d_in[1];  // [16,8192,1024]
  const float* W_q     = (const float*)d_in[2];  // [1024,1024]
  const float* W_k     = (const float*)d_in[3];  // [1024,1024]
  const float* w_v     = (const float*)d_in[4];  // [1024,1]
  float* out = (float*)d_out;                    // [16,8192] fp32

  float* qh           = (float*)d_ws;                                  // 64 KB
  unsigned short* WkT = (unsigned short*)((char*)d_ws + 64 * 1024);    // 2 MB

  qh_kernel<<<dim3(BB, HH / 256), 256, 0, stream>>>(queries, W_q, qh);
  wkt_kernel<<<dim3((HH / 32) * (DD / 32)), 256, 0, stream>>>(W_k, WkT);
  fused_kernel<<<dim3((BB * LK) / 32), 256, 0, stream>>>(keys, WkT, qh, w_v, out);
}